// Round 1
// baseline (144.296 us; speedup 1.0000x reference)
//
#include <hip/hip_runtime.h>
#include <math.h>

#define DDIM 4096
#define EDIM 64
#define NROWS 16384
#define NS 4
#define KC (DDIM / NS)   // 1024 per K-slice
#define DT 128           // K-tile staged in LDS
#define TOPK_K 8

// Pass 1: partial[s][row][e] = sum_{d in slice s} x[row][d] * Wr[d][e]
// Block: 256 threads = 4 waves. lane = row (64 rows/block), wave -> 16 experts.
__global__ __launch_bounds__(256) void router_pass1(
    const float* __restrict__ x, const float* __restrict__ Wr,
    float* __restrict__ partial) {
  const int tid  = threadIdx.x;
  const int lane = tid & 63;
  const int wave = tid >> 6;
  const int row0 = blockIdx.x * 64;
  const int k0   = blockIdx.y * KC;
  // force wave-uniform expert base so Wr loads become scalar (s_load) broadcasts
  const int e0 = __builtin_amdgcn_readfirstlane(wave * 16);

  // 64 rows x 32 float4 slots, XOR-swizzled: slot = c ^ (r&7)
  __shared__ float4 xs[64 * (DT / 4)];

  float acc[16];
  #pragma unroll
  for (int e = 0; e < 16; ++e) acc[e] = 0.f;

  for (int t = 0; t < KC; t += DT) {
    __syncthreads();
    // stage 64 rows x DT floats, coalesced; 2048 float4 / 256 threads = 8 each
    #pragma unroll
    for (int i = 0; i < (64 * (DT / 4)) / 256; ++i) {
      int fi = tid + i * 256;
      int r  = fi >> 5;        // 32 float4 per row
      int c  = fi & 31;
      float4 v = *(const float4*)(x + (size_t)(row0 + r) * DDIM + k0 + t + c * 4);
      xs[r * 32 + (c ^ (r & 7))] = v;
    }
    __syncthreads();
    // compute: lane's row, 16 experts, 128 K values
    for (int c = 0; c < DT / 4; ++c) {
      float4 xv = xs[lane * 32 + (c ^ (lane & 7))];
      int dg = k0 + t + c * 4;
      #pragma unroll
      for (int j = 0; j < 4; ++j) {
        const float* wrow = Wr + (size_t)(dg + j) * EDIM + e0;  // uniform -> s_load
        float xj = (j == 0) ? xv.x : (j == 1) ? xv.y : (j == 2) ? xv.z : xv.w;
        #pragma unroll
        for (int e = 0; e < 16; ++e)
          acc[e] = fmaf(xj, wrow[e], acc[e]);
      }
    }
  }
  float* p = partial + ((size_t)blockIdx.y * NROWS + row0 + lane) * EDIM + e0;
  #pragma unroll
  for (int e = 0; e < 16; e += 4)
    *(float4*)(p + e) = make_float4(acc[e], acc[e + 1], acc[e + 2], acc[e + 3]);
}

// Pass 2: reduce NS partials + bias, top-8 (jax tie-break: lower index first),
// sparse softmax. One wave per row, lane = expert.
__global__ __launch_bounds__(256) void router_pass2(
    const float* __restrict__ partial, const float* __restrict__ br,
    float* __restrict__ out_scores, float* __restrict__ out_idx) {
  const int lane = threadIdx.x & 63;
  const int row  = blockIdx.x * 4 + (threadIdx.x >> 6);

  float v = br[lane];
  #pragma unroll
  for (int s = 0; s < NS; ++s)
    v += partial[((size_t)s * NROWS + row) * EDIM + lane];

  const float v0 = v;
  float cur = v;
  bool sel  = false;
  int myidx = 0;
  float maxv = 0.f;

  #pragma unroll
  for (int k = 0; k < TOPK_K; ++k) {
    float bv = cur;
    int   bi = lane;
    #pragma unroll
    for (int off = 32; off; off >>= 1) {
      float ov = __shfl_xor(bv, off);
      int   oi = __shfl_xor(bi, off);
      if (ov > bv || (ov == bv && oi < bi)) { bv = ov; bi = oi; }
    }
    if (k == 0) maxv = bv;
    if (lane == k) myidx = bi;          // lane k holds k-th index
    if (lane == bi) { cur = -__builtin_inff(); sel = true; }
  }

  float p = sel ? expf(v0 - maxv) : 0.f;
  float ssum = p;
  #pragma unroll
  for (int off = 32; off; off >>= 1) ssum += __shfl_xor(ssum, off);

  out_scores[(size_t)row * EDIM + lane] = p / ssum;
  if (lane < TOPK_K)
    out_idx[(size_t)row * TOPK_K + lane] = (float)myidx;
}

extern "C" void kernel_launch(void* const* d_in, const int* in_sizes, int n_in,
                              void* d_out, int out_size, void* d_ws, size_t ws_size,
                              hipStream_t stream) {
  const float* x  = (const float*)d_in[0];
  const float* Wr = (const float*)d_in[1];
  const float* br = (const float*)d_in[2];
  // d_in[3] (Wn), d_in[4] (bn): dead code in the reference — intentionally unused.

  float* partial    = (float*)d_ws;            // NS * 16384 * 64 * 4 = 16 MiB
  float* out_scores = (float*)d_out;
  float* out_idx    = out_scores + (size_t)NROWS * EDIM;

  dim3 g1(NROWS / 64, NS);
  router_pass1<<<g1, 256, 0, stream>>>(x, Wr, partial);
  router_pass2<<<NROWS / 4, 256, 0, stream>>>(partial, br, out_scores, out_idx);
}